// Round 7
// baseline (42.935 us; speedup 1.0000x reference)
//
#include <hip/hip_runtime.h>
#include <hip/hip_bf16.h>

// Problem constants
#define B_  16
#define S1_ 128
#define S2_ 256
#define H_  256
#define HM_ 512
#define QB  4   // q-rows per attn block

typedef _Float16 hf2 __attribute__((ext_vector_type(2)));
typedef _Float16 hf4 __attribute__((ext_vector_type(4)));
typedef _Float16 hf8 __attribute__((ext_vector_type(8)));
typedef float    f32x4 __attribute__((ext_vector_type(4)));

static __device__ inline hf2 u2h(unsigned u) {
    union { unsigned u; hf2 h; } x; x.u = u; return x.h;
}

static __device__ inline float dot2(hf2 a, hf2 b, float c) {
#if __has_builtin(__builtin_amdgcn_fdot2)
    return __builtin_amdgcn_fdot2(a, b, c, false);
#else
    asm("v_dot2_f32_f16 %0, %1, %2, %0" : "+v"(c) : "v"(a), "v"(b));
    return c;
#endif
}

// ---------------------------------------------------------------------------
// cvtW: Wt[n][k] = fp16(W1[k][n]) via LDS-transposed 32x32 tiles.
// grid 256 blocks (16x16 tiles), 256 threads. Both global sides coalesced.
// ---------------------------------------------------------------------------
__global__ __launch_bounds__(256) void cvtW_kernel(
    const float* __restrict__ W1, _Float16* __restrict__ Wt)
{
    __shared__ float Ls[32][33];
    const int t  = threadIdx.x;
    const int kt = blockIdx.x & 15, nt = blockIdx.x >> 4;

    // read W1[kt*32 + r][nt*32 + c4*4 ..] (float4, coalesced)
    {
        const int r = t >> 3, c4 = (t & 7) * 4;
        float4 v = *(const float4*)(W1 + (size_t)(kt * 32 + r) * HM_ + nt * 32 + c4);
        Ls[r][c4 + 0] = v.x; Ls[r][c4 + 1] = v.y;
        Ls[r][c4 + 2] = v.z; Ls[r][c4 + 3] = v.w;
    }
    __syncthreads();
    // write Wt[nt*32 + n][kt*32 + k4*4 ..] (hf4 = 8B, coalesced)
    {
        const int n = t >> 3, k4 = (t & 7) * 4;
        hf4 h = { (_Float16)Ls[k4 + 0][n], (_Float16)Ls[k4 + 1][n],
                  (_Float16)Ls[k4 + 2][n], (_Float16)Ls[k4 + 3][n] };
        *(hf4*)(Wt + (size_t)(nt * 32 + n) * HM_ + kt * 32 + k4) = h;
    }
}

// ---------------------------------------------------------------------------
// proj_mfma: one launch, 768 blocks, 256 threads (4 waves).
//   blocks [0,256):   QPh  = fp16( query @ W1[:256] )          [2048][512]
//   blocks [256,768): KPTh = fp16( key @ W1[256:] + b1 )  [b][h/8][k][8]
// 64x64 tile, FULL K=256 staged in LDS once (one barrier), then 8 unrolled
// MFMA steps (mfma_f32_16x16x32_f16, fp32 acc). Wave tile 32x32 (2A+2B
// reads per 4 MFMA). Rows padded to 264 halves -> 2-way (free) conflicts.
// ---------------------------------------------------------------------------
__global__ __launch_bounds__(256) void proj_mfma_kernel(
    const float* __restrict__ query,
    const float* __restrict__ key,
    const _Float16* __restrict__ Wt,   // [512 n][512 k]
    const float* __restrict__ b1,
    _Float16* __restrict__ QPh,        // [2048][512]
    _Float16* __restrict__ KPTh)       // [16][64][256][8]
{
    __shared__ _Float16 Xh[64][264];
    __shared__ _Float16 Wh[64][264];

    const int t   = threadIdx.x;
    const int bid = blockIdx.x;
    const bool modeK = bid >= 256;
    const int lb    = modeK ? bid - 256 : bid;
    const int mtile = lb >> 3, ntile = lb & 7;
    const int m0 = mtile * 64, n0 = ntile * 64;
    const float* X = modeK ? key : query;
    const int kw = modeK ? 256 : 0;

    // stage whole X tile (f32 -> f16) and W tile (f16), coalesced
#pragma unroll 2
    for (int i = 0; i < 8; ++i) {
        const int g   = t + i * 256;          // 0..2047 (8-half chunks)
        const int row = g >> 5, c8 = (g & 31) * 8;
        float4 xa = *(const float4*)(X + (size_t)(m0 + row) * H_ + c8);
        float4 xb = *(const float4*)(X + (size_t)(m0 + row) * H_ + c8 + 4);
        hf8 xh = { (_Float16)xa.x, (_Float16)xa.y, (_Float16)xa.z, (_Float16)xa.w,
                   (_Float16)xb.x, (_Float16)xb.y, (_Float16)xb.z, (_Float16)xb.w };
        *(hf8*)&Xh[row][c8] = xh;
        uint4 wv = *(const uint4*)(Wt + (size_t)(n0 + row) * HM_ + kw + c8);
        *(uint4*)&Wh[row][c8] = wv;
    }
    __syncthreads();

    const int lane = t & 63, wid = t >> 6;
    const int wr = (wid >> 1) * 32;      // wave m-base
    const int wc = (wid & 1) * 32;       // wave n-base
    const int fr = lane & 15;            // fragment fast index
    const int fk = (lane >> 4) * 8;      // k sub-block base

    f32x4 acc[2][2] = {};

#pragma unroll
    for (int s = 0; s < 8; ++s) {
        const int kb = s * 32 + fk;
        hf8 a0 = *(const hf8*)&Xh[wr + fr][kb];
        hf8 a1 = *(const hf8*)&Xh[wr + 16 + fr][kb];
        hf8 b0 = *(const hf8*)&Wh[wc + fr][kb];
        hf8 b1v = *(const hf8*)&Wh[wc + 16 + fr][kb];
        acc[0][0] = __builtin_amdgcn_mfma_f32_16x16x32_f16(a0, b0,  acc[0][0], 0, 0, 0);
        acc[0][1] = __builtin_amdgcn_mfma_f32_16x16x32_f16(a0, b1v, acc[0][1], 0, 0, 0);
        acc[1][0] = __builtin_amdgcn_mfma_f32_16x16x32_f16(a1, b0,  acc[1][0], 0, 0, 0);
        acc[1][1] = __builtin_amdgcn_mfma_f32_16x16x32_f16(a1, b1v, acc[1][1], 0, 0, 0);
    }

    // epilogue: D col = lane&15, row = (lane>>4)*4 + reg (m89-verified)
    if (!modeK) {
#pragma unroll
        for (int i = 0; i < 2; ++i)
#pragma unroll
        for (int j = 0; j < 2; ++j) {
            const int n = n0 + wc + j * 16 + fr;
#pragma unroll
            for (int r = 0; r < 4; ++r) {
                const int m = m0 + wr + i * 16 + (lane >> 4) * 4 + r;
                QPh[(size_t)m * HM_ + n] = (_Float16)acc[i][j][r];
            }
        }
    } else {
#pragma unroll
        for (int i = 0; i < 2; ++i)
#pragma unroll
        for (int j = 0; j < 2; ++j) {
            const int n = n0 + wc + j * 16 + fr;
            const float bv = b1[n];
#pragma unroll
            for (int r = 0; r < 4; ++r) {
                const int m    = m0 + wr + i * 16 + (lane >> 4) * 4 + r;  // key row
                const int bb   = m >> 8, kloc = m & 255;
                KPTh[(((size_t)bb * 64 + (n >> 3)) * 256 + kloc) * 8 + (n & 7)] =
                    (_Float16)(acc[i][j][r] + bv);
            }
        }
    }
}

// ---------------------------------------------------------------------------
// attn: block = (b, 4 q-rows), 512 threads: k = t&255, hb = t>>8.
//  phase 1 (fp16): per 8-h chunk: kv = 16B coalesced global, qv/w4 = 16B LDS
//           broadcast; v_pk_add/v_pk_max/v_dot2 -> f32 acc.
//  phase 2: combine halves + b2, mask, exp (fp32).
//  phase 3: rowsum; PV 8-way distinct split-k; LDS combine.
// ---------------------------------------------------------------------------
__global__ __launch_bounds__(512, 4) void attn_kernel(
    const _Float16* __restrict__ QPh,  // [B*S1][HM]
    const _Float16* __restrict__ KPTh, // [B][HM/8][S2][8] (b1 folded)
    const float* __restrict__ value,   // [B, S2, H]
    const float* __restrict__ q_mask,  // [B, S1]
    const float* __restrict__ k_mask,  // [B, S2]
    const float* __restrict__ W2,      // [HM]
    const float* __restrict__ b2,      // [1]
    float* __restrict__ out)           // [B, S1, H]
{
    __shared__ __align__(16) _Float16 qp_h[QB][HM_];   // 4 KB
    __shared__ __align__(16) _Float16 w2_h[HM_];       // 1 KB
    __shared__ __align__(16) float    Ap[2][QB][S2_];  // 8 KB
    __shared__ __align__(16) float4   opart[8][QB][64];// 32 KB
    __shared__ float rA_s[QB];
    __shared__ float qm_s[QB];
    __shared__ float km_s[S2_];

    const int t  = threadIdx.x;
    const int k  = t & 255;
    const int hb = t >> 8;

    // XCD-aware swizzle: 512 blocks, XCD x gets 64 consecutive wg = 2 b's
    const int orig = blockIdx.x + (int)gridDim.x * blockIdx.y;  // 0..511
    const int wg   = (orig & 7) * 64 + (orig >> 3);
    const int q0   = (wg & 31) * QB;
    const int b    = wg >> 5;

    // stage qp (fp16), w2 (cvt), masks
    {
        if (t < 256) {
            const uint4* src = (const uint4*)(QPh + (size_t)(b * S1_ + q0) * HM_);
            ((uint4*)&qp_h[0][0])[t] = src[t];
            km_s[t] = k_mask[b * S2_ + t];
        } else if (t < 256 + 128) {
            const int i = t - 256;
            float4 wvv = ((const float4*)W2)[i];
            hf4 hv = { (_Float16)wvv.x, (_Float16)wvv.y,
                       (_Float16)wvv.z, (_Float16)wvv.w };
            *(hf4*)&w2_h[i * 4] = hv;
        } else if (t < 256 + 128 + QB) {
            const int i = t - (256 + 128);
            qm_s[i] = q_mask[b * S1_ + q0 + i];
        }
    }
    __syncthreads();

    // phase 1: score partials over this thread's h half (32 chunks of 8 h)
    float accs[QB] = {0.f, 0.f, 0.f, 0.f};
    const uint4* kp8 = (const uint4*)KPTh + ((size_t)b * 64 + hb * 32) * S2_ + k;

    for (int c = 0; c < 32; ++c) {
        uint4 kvu = kp8[(size_t)c * S2_];
        const int hoff = hb * (HM_ / 2) + c * 8;
        uint4 w4u = *(const uint4*)&w2_h[hoff];
        hf2 kv0 = u2h(kvu.x), kv1 = u2h(kvu.y), kv2 = u2h(kvu.z), kv3 = u2h(kvu.w);
        hf2 wv0 = u2h(w4u.x), wv1 = u2h(w4u.y), wv2 = u2h(w4u.z), wv3 = u2h(w4u.w);
        const hf2 zero = (hf2)(_Float16)0;
#pragma unroll
        for (int q = 0; q < QB; ++q) {
            uint4 qvu = *(const uint4*)&qp_h[q][hoff];
            hf2 s;
            s = __builtin_elementwise_max(u2h(qvu.x) + kv0, zero);
            accs[q] = dot2(s, wv0, accs[q]);
            s = __builtin_elementwise_max(u2h(qvu.y) + kv1, zero);
            accs[q] = dot2(s, wv1, accs[q]);
            s = __builtin_elementwise_max(u2h(qvu.z) + kv2, zero);
            accs[q] = dot2(s, wv2, accs[q]);
            s = __builtin_elementwise_max(u2h(qvu.w) + kv3, zero);
            accs[q] = dot2(s, wv3, accs[q]);
        }
    }
#pragma unroll
    for (int q = 0; q < QB; ++q) Ap[hb][q][k] = accs[q];
    __syncthreads();

    // phase 2: combine halves, mask, exp (in place into Ap[0])
    {
        const float b2v = b2[0];
#pragma unroll
        for (int i = 0; i < 2; ++i) {
            const int idx = t + i * 512;           // 0..1023
            const int q = idx >> 8, kk = idx & 255;
            float sc = Ap[0][q][kk] + Ap[1][q][kk] + b2v;
            Ap[0][q][kk] = (qm_s[q] * km_s[kk] == 0.f) ? 0.f : __expf(sc);
        }
    }
    __syncthreads();

    // row sums: waves 0..3 (one per q-row), 64-lane butterfly
    if (t < QB * 64) {
        const int q = t >> 6, lane = t & 63;
        float p = Ap[0][q][lane] + Ap[0][q][lane + 64] +
                  Ap[0][q][lane + 128] + Ap[0][q][lane + 192];
#pragma unroll
        for (int m = 32; m >= 1; m >>= 1) p += __shfl_xor(p, m, 64);
        if (lane == 0) rA_s[q] = 1.0f / fmaxf(p, 2e-15f);
    }
    __syncthreads();

    // PV: wave w owns value rows [w*32, w*32+32) for ALL 4 q (no redundancy)
    {
        const int w = t >> 6, lane = t & 63;
        const float4* vb = (const float4*)(value + (size_t)b * S2_ * H_)
                           + (size_t)(w * 32) * (H_ / 4) + lane;
        float4 o[QB];
#pragma unroll
        for (int q = 0; q < QB; ++q) o[q] = make_float4(0.f, 0.f, 0.f, 0.f);
#pragma unroll 4
        for (int kk = 0; kk < 32; ++kk) {
            float4 v = vb[(size_t)kk * (H_ / 4)];
#pragma unroll
            for (int q = 0; q < QB; ++q) {
                float a = Ap[0][q][w * 32 + kk];
                o[q].x = fmaf(a, v.x, o[q].x); o[q].y = fmaf(a, v.y, o[q].y);
                o[q].z = fmaf(a, v.z, o[q].z); o[q].w = fmaf(a, v.w, o[q].w);
            }
        }
#pragma unroll
        for (int q = 0; q < QB; ++q) opart[w][q][lane] = o[q];
    }
    __syncthreads();

    // combine 8 partials, normalize, store
    if (t < QB * 64) {
        const int q = t >> 6, lane = t & 63;
        float4 s = make_float4(0.f, 0.f, 0.f, 0.f);
#pragma unroll
        for (int w = 0; w < 8; ++w) {
            float4 p = opart[w][q][lane];
            s.x += p.x; s.y += p.y; s.z += p.z; s.w += p.w;
        }
        const float r = rA_s[q];
        s.x *= r; s.y *= r; s.z *= r; s.w *= r;
        *(float4*)(out + (size_t)(b * S1_ + q0 + q) * H_ + lane * 4) = s;
    }
}

extern "C" void kernel_launch(void* const* d_in, const int* in_sizes, int n_in,
                              void* d_out, int out_size, void* d_ws, size_t ws_size,
                              hipStream_t stream) {
    const float* query  = (const float*)d_in[0];  // [16,128,256]
    const float* key    = (const float*)d_in[1];  // [16,256,256]
    const float* value  = (const float*)d_in[2];  // [16,256,256]
    const float* q_mask = (const float*)d_in[3];  // [16,128]
    const float* k_mask = (const float*)d_in[4];  // [16,256]
    const float* W1     = (const float*)d_in[5];  // [512,512]
    const float* b1     = (const float*)d_in[6];  // [512]
    const float* W2     = (const float*)d_in[7];  // [512,1]
    const float* b2     = (const float*)d_in[8];  // [1]
    float*       out    = (float*)d_out;

    _Float16* QPh  = (_Float16*)d_ws;                  // [2048][512]   2 MB
    _Float16* KPTh = QPh  + (size_t)B_ * S1_ * HM_;    // [16][64][256][8] 4 MB
    _Float16* Wt   = KPTh + (size_t)B_ * S2_ * HM_;    // [512][512]  0.5 MB

    // Wt[n][k] = fp16(W1[k][n])
    cvtW_kernel<<<256, 256, 0, stream>>>(W1, Wt);

    // merged MFMA projections: blocks [0,256) -> QPh, [256,768) -> KPTh
    proj_mfma_kernel<<<768, 256, 0, stream>>>(query, key, Wt, b1, QPh, KPTh);

    attn_kernel<<<dim3(S1_ / QB, B_), 512, 0, stream>>>(
        QPh, KPTh, value, q_mask, k_mask, W2, b2, out);
}

// Round 8
// 40.935 us; speedup vs baseline: 1.0489x; 1.0489x over previous
//
#include <hip/hip_runtime.h>
#include <hip/hip_bf16.h>

// Problem constants
#define B_  16
#define S1_ 128
#define S2_ 256
#define H_  256
#define HM_ 512
#define QB  4   // q-rows per attn block

typedef _Float16 hf2 __attribute__((ext_vector_type(2)));
typedef _Float16 hf4 __attribute__((ext_vector_type(4)));
typedef _Float16 hf8 __attribute__((ext_vector_type(8)));
typedef float    f32x4 __attribute__((ext_vector_type(4)));

static __device__ inline hf2 u2h(unsigned u) {
    union { unsigned u; hf2 h; } x; x.u = u; return x.h;
}

static __device__ inline float dot2(hf2 a, hf2 b, float c) {
#if __has_builtin(__builtin_amdgcn_fdot2)
    return __builtin_amdgcn_fdot2(a, b, c, false);
#else
    asm("v_dot2_f32_f16 %0, %1, %2, %0" : "+v"(c) : "v"(a), "v"(b));
    return c;
#endif
}

// ---------------------------------------------------------------------------
// cvtWB: repack W1 [512 k][512 n] f32 into MFMA B-fragment order, fp16:
//   WB[((kblk*32 + nblk)*64 + lane)*8 + j] = W1[kblk*32 + (lane>>4)*8 + j]
//                                              [nblk*16 + (lane&15)]
// so a B-frag load in proj is one coalesced hf8 per lane.
// 32768 threads = 128 blocks x 256. Writes 16B coalesced; reads L2-served.
// ---------------------------------------------------------------------------
__global__ __launch_bounds__(256) void cvtWB_kernel(
    const float* __restrict__ W1, _Float16* __restrict__ WB)
{
    const int idx  = blockIdx.x * 256 + threadIdx.x;  // 0..32767
    const int lane = idx & 63;
    const int nblk = (idx >> 6) & 31;
    const int kblk = idx >> 11;                       // 0..15
    const int n    = nblk * 16 + (lane & 15);
    const int k0   = kblk * 32 + (lane >> 4) * 8;
    hf8 v;
#pragma unroll
    for (int j = 0; j < 8; ++j)
        v[j] = (_Float16)W1[(size_t)(k0 + j) * HM_ + n];
    *(hf8*)(WB + (size_t)idx * 8) = v;
}

// ---------------------------------------------------------------------------
// proj_mfma: grid 384 blocks x 512 thr (8 waves).
//   blocks [0,128):   QPh  = fp16( query @ W1[:256] )       [2048][512]
//   blocks [128,384): KPTh = fp16( key @ W1[256:] + b1 ) [b][h/8][k][8]
// Block tile: 16 m-rows x ALL 512 n (X staged once grid-wide, 8.4 KB LDS).
// Wave w owns n in [w*64, w*64+64): acc = 4 n-frags of 16x16.
// B operands stream from WB (frag-order, coalesced, L2-resident).
// ---------------------------------------------------------------------------
__global__ __launch_bounds__(512, 4) void proj_mfma_kernel(
    const float* __restrict__ query,
    const float* __restrict__ key,
    const _Float16* __restrict__ WB,   // frag-order W (both halves)
    const float* __restrict__ b1,
    _Float16* __restrict__ QPh,        // [2048][512]
    _Float16* __restrict__ KPTh)       // [16][64][256][8]
{
    __shared__ _Float16 Xh[16][264];

    const int t   = threadIdx.x;
    const int bid = blockIdx.x;
    const bool modeK = bid >= 128;
    const int m0  = (modeK ? bid - 128 : bid) * 16;
    const float* X = modeK ? key : query;
    const int kb  = modeK ? 8 : 0;     // kblk base into WB

    // stage X tile (16 rows x 256 k), fp32 -> fp16, each row once grid-wide
    {
        const int row = t >> 5, c8 = (t & 31) * 8;
        const float* xs = X + (size_t)(m0 + row) * H_ + c8;
        float4 xa = *(const float4*)xs;
        float4 xb = *(const float4*)(xs + 4);
        hf8 xh = { (_Float16)xa.x, (_Float16)xa.y, (_Float16)xa.z, (_Float16)xa.w,
                   (_Float16)xb.x, (_Float16)xb.y, (_Float16)xb.z, (_Float16)xb.w };
        *(hf8*)&Xh[row][c8] = xh;
    }
    __syncthreads();

    const int lane = t & 63, w = t >> 6;
    const int fr = lane & 15;            // m for A / n-within-frag for B/D
    const int fk = (lane >> 4) * 8;      // k slot base

    f32x4 acc[4] = {};

#pragma unroll
    for (int s = 0; s < 8; ++s) {
        hf8 a = *(const hf8*)&Xh[fr][s * 32 + fk];
        const _Float16* bp =
            WB + ((((size_t)(kb + s) * 32 + w * 4) * 64) + lane) * 8;
#pragma unroll
        for (int nf = 0; nf < 4; ++nf) {
            hf8 bv = *(const hf8*)(bp + (size_t)nf * 64 * 8);
            acc[nf] = __builtin_amdgcn_mfma_f32_16x16x32_f16(a, bv, acc[nf], 0, 0, 0);
        }
    }

    // epilogue: D col = lane&15, row = (lane>>4)*4 + reg
    if (!modeK) {
#pragma unroll
        for (int nf = 0; nf < 4; ++nf) {
            const int n = w * 64 + nf * 16 + fr;
#pragma unroll
            for (int r = 0; r < 4; ++r) {
                const int m = m0 + (lane >> 4) * 4 + r;
                QPh[(size_t)m * HM_ + n] = (_Float16)acc[nf][r];
            }
        }
    } else {
#pragma unroll
        for (int nf = 0; nf < 4; ++nf) {
            const int n = w * 64 + nf * 16 + fr;
            const float bv = b1[n];
#pragma unroll
            for (int r = 0; r < 4; ++r) {
                const int m    = m0 + (lane >> 4) * 4 + r;   // key row
                const int bb   = m >> 8, kloc = m & 255;
                KPTh[(((size_t)bb * 64 + (n >> 3)) * 256 + kloc) * 8 + (n & 7)] =
                    (_Float16)(acc[nf][r] + bv);
            }
        }
    }
}

// ---------------------------------------------------------------------------
// attn: block = (b, 4 q-rows), 512 threads: k = t&255, hb = t>>8.
//  phase 1 (fp16): per 8-h chunk: kv = 16B coalesced global, qv/w4 = 16B LDS
//           broadcast; v_pk_add/v_pk_max/v_dot2 -> f32 acc.
//  phase 2: combine halves + b2, mask, exp (fp32).
//  phase 3: rowsum; PV 8-way distinct split-k; LDS combine.
// ---------------------------------------------------------------------------
__global__ __launch_bounds__(512, 4) void attn_kernel(
    const _Float16* __restrict__ QPh,  // [B*S1][HM]
    const _Float16* __restrict__ KPTh, // [B][HM/8][S2][8] (b1 folded)
    const float* __restrict__ value,   // [B, S2, H]
    const float* __restrict__ q_mask,  // [B, S1]
    const float* __restrict__ k_mask,  // [B, S2]
    const float* __restrict__ W2,      // [HM]
    const float* __restrict__ b2,      // [1]
    float* __restrict__ out)           // [B, S1, H]
{
    __shared__ __align__(16) _Float16 qp_h[QB][HM_];   // 4 KB
    __shared__ __align__(16) _Float16 w2_h[HM_];       // 1 KB
    __shared__ __align__(16) float    Ap[2][QB][S2_];  // 8 KB
    __shared__ __align__(16) float4   opart[8][QB][64];// 32 KB
    __shared__ float rA_s[QB];
    __shared__ float qm_s[QB];
    __shared__ float km_s[S2_];

    const int t  = threadIdx.x;
    const int k  = t & 255;
    const int hb = t >> 8;

    // XCD-aware swizzle: 512 blocks, XCD x gets 64 consecutive wg = 2 b's
    const int orig = blockIdx.x + (int)gridDim.x * blockIdx.y;  // 0..511
    const int wg   = (orig & 7) * 64 + (orig >> 3);
    const int q0   = (wg & 31) * QB;
    const int b    = wg >> 5;

    // stage qp (fp16), w2 (cvt), masks
    {
        if (t < 256) {
            const uint4* src = (const uint4*)(QPh + (size_t)(b * S1_ + q0) * HM_);
            ((uint4*)&qp_h[0][0])[t] = src[t];
            km_s[t] = k_mask[b * S2_ + t];
        } else if (t < 256 + 128) {
            const int i = t - 256;
            float4 wvv = ((const float4*)W2)[i];
            hf4 hv = { (_Float16)wvv.x, (_Float16)wvv.y,
                       (_Float16)wvv.z, (_Float16)wvv.w };
            *(hf4*)&w2_h[i * 4] = hv;
        } else if (t < 256 + 128 + QB) {
            const int i = t - (256 + 128);
            qm_s[i] = q_mask[b * S1_ + q0 + i];
        }
    }
    __syncthreads();

    // phase 1: score partials over this thread's h half (32 chunks of 8 h)
    float accs[QB] = {0.f, 0.f, 0.f, 0.f};
    const uint4* kp8 = (const uint4*)KPTh + ((size_t)b * 64 + hb * 32) * S2_ + k;

    for (int c = 0; c < 32; ++c) {
        uint4 kvu = kp8[(size_t)c * S2_];
        const int hoff = hb * (HM_ / 2) + c * 8;
        uint4 w4u = *(const uint4*)&w2_h[hoff];
        hf2 kv0 = u2h(kvu.x), kv1 = u2h(kvu.y), kv2 = u2h(kvu.z), kv3 = u2h(kvu.w);
        hf2 wv0 = u2h(w4u.x), wv1 = u2h(w4u.y), wv2 = u2h(w4u.z), wv3 = u2h(w4u.w);
        const hf2 zero = (hf2)(_Float16)0;
#pragma unroll
        for (int q = 0; q < QB; ++q) {
            uint4 qvu = *(const uint4*)&qp_h[q][hoff];
            hf2 s;
            s = __builtin_elementwise_max(u2h(qvu.x) + kv0, zero);
            accs[q] = dot2(s, wv0, accs[q]);
            s = __builtin_elementwise_max(u2h(qvu.y) + kv1, zero);
            accs[q] = dot2(s, wv1, accs[q]);
            s = __builtin_elementwise_max(u2h(qvu.z) + kv2, zero);
            accs[q] = dot2(s, wv2, accs[q]);
            s = __builtin_elementwise_max(u2h(qvu.w) + kv3, zero);
            accs[q] = dot2(s, wv3, accs[q]);
        }
    }
#pragma unroll
    for (int q = 0; q < QB; ++q) Ap[hb][q][k] = accs[q];
    __syncthreads();

    // phase 2: combine halves, mask, exp (in place into Ap[0])
    {
        const float b2v = b2[0];
#pragma unroll
        for (int i = 0; i < 2; ++i) {
            const int idx = t + i * 512;           // 0..1023
            const int q = idx >> 8, kk = idx & 255;
            float sc = Ap[0][q][kk] + Ap[1][q][kk] + b2v;
            Ap[0][q][kk] = (qm_s[q] * km_s[kk] == 0.f) ? 0.f : __expf(sc);
        }
    }
    __syncthreads();

    // row sums: waves 0..3 (one per q-row), 64-lane butterfly
    if (t < QB * 64) {
        const int q = t >> 6, lane = t & 63;
        float p = Ap[0][q][lane] + Ap[0][q][lane + 64] +
                  Ap[0][q][lane + 128] + Ap[0][q][lane + 192];
#pragma unroll
        for (int m = 32; m >= 1; m >>= 1) p += __shfl_xor(p, m, 64);
        if (lane == 0) rA_s[q] = 1.0f / fmaxf(p, 2e-15f);
    }
    __syncthreads();

    // PV: wave w owns value rows [w*32, w*32+32) for ALL 4 q (no redundancy)
    {
        const int w = t >> 6, lane = t & 63;
        const float4* vb = (const float4*)(value + (size_t)b * S2_ * H_)
                           + (size_t)(w * 32) * (H_ / 4) + lane;
        float4 o[QB];
#pragma unroll
        for (int q = 0; q < QB; ++q) o[q] = make_float4(0.f, 0.f, 0.f, 0.f);
#pragma unroll 4
        for (int kk = 0; kk < 32; ++kk) {
            float4 v = vb[(size_t)kk * (H_ / 4)];
#pragma unroll
            for (int q = 0; q < QB; ++q) {
                float a = Ap[0][q][w * 32 + kk];
                o[q].x = fmaf(a, v.x, o[q].x); o[q].y = fmaf(a, v.y, o[q].y);
                o[q].z = fmaf(a, v.z, o[q].z); o[q].w = fmaf(a, v.w, o[q].w);
            }
        }
#pragma unroll
        for (int q = 0; q < QB; ++q) opart[w][q][lane] = o[q];
    }
    __syncthreads();

    // combine 8 partials, normalize, store
    if (t < QB * 64) {
        const int q = t >> 6, lane = t & 63;
        float4 s = make_float4(0.f, 0.f, 0.f, 0.f);
#pragma unroll
        for (int w = 0; w < 8; ++w) {
            float4 p = opart[w][q][lane];
            s.x += p.x; s.y += p.y; s.z += p.z; s.w += p.w;
        }
        const float r = rA_s[q];
        s.x *= r; s.y *= r; s.z *= r; s.w *= r;
        *(float4*)(out + (size_t)(b * S1_ + q0 + q) * H_ + lane * 4) = s;
    }
}

extern "C" void kernel_launch(void* const* d_in, const int* in_sizes, int n_in,
                              void* d_out, int out_size, void* d_ws, size_t ws_size,
                              hipStream_t stream) {
    const float* query  = (const float*)d_in[0];  // [16,128,256]
    const float* key    = (const float*)d_in[1];  // [16,256,256]
    const float* value  = (const float*)d_in[2];  // [16,256,256]
    const float* q_mask = (const float*)d_in[3];  // [16,128]
    const float* k_mask = (const float*)d_in[4];  // [16,256]
    const float* W1     = (const float*)d_in[5];  // [512,512]
    const float* b1     = (const float*)d_in[6];  // [512]
    const float* W2     = (const float*)d_in[7];  // [512,1]
    const float* b2     = (const float*)d_in[8];  // [1]
    float*       out    = (float*)d_out;

    _Float16* QPh  = (_Float16*)d_ws;                  // [2048][512]      2 MB
    _Float16* KPTh = QPh  + (size_t)B_ * S1_ * HM_;    // [16][64][256][8] 4 MB
    _Float16* WB   = KPTh + (size_t)B_ * S2_ * HM_;    // frag-order W   0.5 MB

    // WB = frag-order fp16 repack of W1 (both halves)
    cvtWB_kernel<<<128, 256, 0, stream>>>(W1, WB);

    // merged MFMA projections: blocks [0,128) -> QPh, [128,384) -> KPTh
    proj_mfma_kernel<<<384, 512, 0, stream>>>(query, key, WB, b1, QPh, KPTh);

    attn_kernel<<<dim3(S1_ / QB, B_), 512, 0, stream>>>(
        QPh, KPTh, value, q_mask, k_mask, W2, b2, out);
}

// Round 10
// 40.128 us; speedup vs baseline: 1.0700x; 1.0201x over previous
//
#include <hip/hip_runtime.h>
#include <hip/hip_bf16.h>

// Problem constants
#define B_  16
#define S1_ 128
#define S2_ 256
#define H_  256
#define HM_ 512
#define QB  4   // q-rows per attn block

typedef _Float16 hf2 __attribute__((ext_vector_type(2)));
typedef _Float16 hf4 __attribute__((ext_vector_type(4)));
typedef _Float16 hf8 __attribute__((ext_vector_type(8)));
typedef float    f32x4 __attribute__((ext_vector_type(4)));

static __device__ inline hf2 u2h(unsigned u) {
    union { unsigned u; hf2 h; } x; x.u = u; return x.h;
}

static __device__ inline float dot2(hf2 a, hf2 b, float c) {
#if __has_builtin(__builtin_amdgcn_fdot2)
    return __builtin_amdgcn_fdot2(a, b, c, false);
#else
    asm("v_dot2_f32_f16 %0, %1, %2, %0" : "+v"(c) : "v"(a), "v"(b));
    return c;
#endif
}

// ---------------------------------------------------------------------------
// cvtWB: repack W1 [512 k][512 n] f32 into MFMA B-fragment order, fp16:
//   WB[((kblk*32 + nblk)*64 + lane)*8 + j] = W1[kblk*32 + (lane>>4)*8 + j]
//                                              [nblk*16 + (lane&15)]
// ---------------------------------------------------------------------------
__global__ __launch_bounds__(256) void cvtWB_kernel(
    const float* __restrict__ W1, _Float16* __restrict__ WB)
{
    const int idx  = blockIdx.x * 256 + threadIdx.x;  // 0..32767
    const int lane = idx & 63;
    const int nblk = (idx >> 6) & 31;
    const int kblk = idx >> 11;                       // 0..15
    const int n    = nblk * 16 + (lane & 15);
    const int k0   = kblk * 32 + (lane >> 4) * 8;
    hf8 v;
#pragma unroll
    for (int j = 0; j < 8; ++j)
        v[j] = (_Float16)W1[(size_t)(k0 + j) * HM_ + n];
    *(hf8*)(WB + (size_t)idx * 8) = v;
}

// ---------------------------------------------------------------------------
// proj_mfma: grid 384 blocks x 512 thr (8 waves).
//   blocks [0,128):   QPh  = fp16( query @ W1[:256] )       [2048][512]
//   blocks [128,384): KPTh = fp16( key @ W1[256:] + b1 ) [b][h/8][k][8]
// Block tile: 16 m-rows x ALL 512 n. B operands stream from WB (frag-order,
// coalesced, L2-resident). Epilogue goes through an LDS [16][512] fp16 tile
// (reusing the X-staging buffer) so ALL global stores are coalesced uint4.
// FIX vs r9: QPh store decomposition is 16 rows x 64 uint4 (row=idx>>6),
// 2 passes — r9's idx>>7/(idx&127) read past the row and stomped output.
// ---------------------------------------------------------------------------
#define ESTR 520   // LDS row stride in halves (pad vs 512)

__global__ __launch_bounds__(512, 4) void proj_mfma_kernel(
    const float* __restrict__ query,
    const float* __restrict__ key,
    const _Float16* __restrict__ WB,   // frag-order W (both halves)
    const float* __restrict__ b1,
    _Float16* __restrict__ QPh,        // [2048][512]
    _Float16* __restrict__ KPTh)       // [16][64][256][8]
{
    __shared__ _Float16 Es[16 * ESTR];   // 16.6 KB: X tile, then C tile

    const int t   = threadIdx.x;
    const int bid = blockIdx.x;
    const bool modeK = bid >= 128;
    const int m0  = (modeK ? bid - 128 : bid) * 16;
    const float* X = modeK ? key : query;
    const int kb  = modeK ? 8 : 0;     // kblk base into WB

    // stage X tile (16 rows x 256 k), fp32 -> fp16, each row once grid-wide
    {
        const int row = t >> 5, c8 = (t & 31) * 8;
        const float* xs = X + (size_t)(m0 + row) * H_ + c8;
        float4 xa = *(const float4*)xs;
        float4 xb = *(const float4*)(xs + 4);
        hf8 xh = { (_Float16)xa.x, (_Float16)xa.y, (_Float16)xa.z, (_Float16)xa.w,
                   (_Float16)xb.x, (_Float16)xb.y, (_Float16)xb.z, (_Float16)xb.w };
        *(hf8*)&Es[row * ESTR + c8] = xh;
    }
    __syncthreads();

    const int lane = t & 63, w = t >> 6;
    const int fr = lane & 15;            // m for A / n-within-frag for B/D
    const int fk = (lane >> 4) * 8;      // k slot base

    f32x4 acc[4] = {};

#pragma unroll
    for (int s = 0; s < 8; ++s) {
        hf8 a = *(const hf8*)&Es[fr * ESTR + s * 32 + fk];
        const _Float16* bp =
            WB + ((((size_t)(kb + s) * 32 + w * 4) * 64) + lane) * 8;
#pragma unroll
        for (int nf = 0; nf < 4; ++nf) {
            hf8 bv = *(const hf8*)(bp + (size_t)nf * 64 * 8);
            acc[nf] = __builtin_amdgcn_mfma_f32_16x16x32_f16(a, bv, acc[nf], 0, 0, 0);
        }
    }

    __syncthreads();     // X-tile reads complete; reuse Es as C tile

    // scatter acc -> Es[mlocal][n] (fp16, bias folded for K mode)
#pragma unroll
    for (int nf = 0; nf < 4; ++nf) {
        const int n = w * 64 + nf * 16 + fr;
        const float bv = modeK ? b1[n] : 0.f;
#pragma unroll
        for (int r = 0; r < 4; ++r) {
            const int ml = (lane >> 4) * 4 + r;      // D row = (lane>>4)*4+reg
            Es[ml * ESTR + n] = (_Float16)(acc[nf][r] + bv);
        }
    }
    __syncthreads();

    // coalesced stores from the C tile
    if (!modeK) {
        // QPh rows: 16 rows x 64 uint4 = 1024 uint4, 2 per thread
#pragma unroll
        for (int p = 0; p < 2; ++p) {
            const int idx = t + p * 512;            // 0..1023
            const int row = idx >> 6, c8 = (idx & 63) * 8;
            *(uint4*)(QPh + (size_t)(m0 + row) * HM_ + c8) =
                *(const uint4*)&Es[row * ESTR + c8];
        }
    } else {
        // KPTh[bb][h8][kbase+kl][0..8) : 64 h8 x 16 kl = 1024 uint4, 2/thread
        const int bb = m0 >> 8, kbase = m0 & 255;
#pragma unroll
        for (int p = 0; p < 2; ++p) {
            const int idx = t + p * 512;            // 0..1023
            const int h8 = idx >> 4, kl = idx & 15;
            *(uint4*)(KPTh + (((size_t)bb * 64 + h8) * 256 + kbase + kl) * 8) =
                *(const uint4*)&Es[kl * ESTR + h8 * 8];
        }
    }
}

// ---------------------------------------------------------------------------
// attn: UNCHANGED from rounds 5-8 (isolating the proj-epilogue A/B).
// ---------------------------------------------------------------------------
__global__ __launch_bounds__(512, 4) void attn_kernel(
    const _Float16* __restrict__ QPh,  // [B*S1][HM]
    const _Float16* __restrict__ KPTh, // [B][HM/8][S2][8] (b1 folded)
    const float* __restrict__ value,   // [B, S2, H]
    const float* __restrict__ q_mask,  // [B, S1]
    const float* __restrict__ k_mask,  // [B, S2]
    const float* __restrict__ W2,      // [HM]
    const float* __restrict__ b2,      // [1]
    float* __restrict__ out)           // [B, S1, H]
{
    __shared__ __align__(16) _Float16 qp_h[QB][HM_];   // 4 KB
    __shared__ __align__(16) _Float16 w2_h[HM_];       // 1 KB
    __shared__ __align__(16) float    Ap[2][QB][S2_];  // 8 KB
    __shared__ __align__(16) float4   opart[8][QB][64];// 32 KB
    __shared__ float rA_s[QB];
    __shared__ float qm_s[QB];
    __shared__ float km_s[S2_];

    const int t  = threadIdx.x;
    const int k  = t & 255;
    const int hb = t >> 8;

    // XCD-aware swizzle: 512 blocks, XCD x gets 64 consecutive wg = 2 b's
    const int orig = blockIdx.x + (int)gridDim.x * blockIdx.y;  // 0..511
    const int wg   = (orig & 7) * 64 + (orig >> 3);
    const int q0   = (wg & 31) * QB;
    const int b    = wg >> 5;

    // stage qp (fp16), w2 (cvt), masks
    {
        if (t < 256) {
            const uint4* src = (const uint4*)(QPh + (size_t)(b * S1_ + q0) * HM_);
            ((uint4*)&qp_h[0][0])[t] = src[t];
            km_s[t] = k_mask[b * S2_ + t];
        } else if (t < 256 + 128) {
            const int i = t - 256;
            float4 wvv = ((const float4*)W2)[i];
            hf4 hv = { (_Float16)wvv.x, (_Float16)wvv.y,
                       (_Float16)wvv.z, (_Float16)wvv.w };
            *(hf4*)&w2_h[i * 4] = hv;
        } else if (t < 256 + 128 + QB) {
            const int i = t - (256 + 128);
            qm_s[i] = q_mask[b * S1_ + q0 + i];
        }
    }
    __syncthreads();

    // phase 1: score partials over this thread's h half (32 chunks of 8 h)
    float accs[QB] = {0.f, 0.f, 0.f, 0.f};
    const uint4* kp8 = (const uint4*)KPTh + ((size_t)b * 64 + hb * 32) * S2_ + k;

    for (int c = 0; c < 32; ++c) {
        uint4 kvu = kp8[(size_t)c * S2_];
        const int hoff = hb * (HM_ / 2) + c * 8;
        uint4 w4u = *(const uint4*)&w2_h[hoff];
        hf2 kv0 = u2h(kvu.x), kv1 = u2h(kvu.y), kv2 = u2h(kvu.z), kv3 = u2h(kvu.w);
        hf2 wv0 = u2h(w4u.x), wv1 = u2h(w4u.y), wv2 = u2h(w4u.z), wv3 = u2h(w4u.w);
        const hf2 zero = (hf2)(_Float16)0;
#pragma unroll
        for (int q = 0; q < QB; ++q) {
            uint4 qvu = *(const uint4*)&qp_h[q][hoff];
            hf2 s;
            s = __builtin_elementwise_max(u2h(qvu.x) + kv0, zero);
            accs[q] = dot2(s, wv0, accs[q]);
            s = __builtin_elementwise_max(u2h(qvu.y) + kv1, zero);
            accs[q] = dot2(s, wv1, accs[q]);
            s = __builtin_elementwise_max(u2h(qvu.z) + kv2, zero);
            accs[q] = dot2(s, wv2, accs[q]);
            s = __builtin_elementwise_max(u2h(qvu.w) + kv3, zero);
            accs[q] = dot2(s, wv3, accs[q]);
        }
    }
#pragma unroll
    for (int q = 0; q < QB; ++q) Ap[hb][q][k] = accs[q];
    __syncthreads();

    // phase 2: combine halves, mask, exp (in place into Ap[0])
    {
        const float b2v = b2[0];
#pragma unroll
        for (int i = 0; i < 2; ++i) {
            const int idx = t + i * 512;           // 0..1023
            const int q = idx >> 8, kk = idx & 255;
            float sc = Ap[0][q][kk] + Ap[1][q][kk] + b2v;
            Ap[0][q][kk] = (qm_s[q] * km_s[kk] == 0.f) ? 0.f : __expf(sc);
        }
    }
    __syncthreads();

    // row sums: waves 0..3 (one per q-row), 64-lane butterfly
    if (t < QB * 64) {
        const int q = t >> 6, lane = t & 63;
        float p = Ap[0][q][lane] + Ap[0][q][lane + 64] +
                  Ap[0][q][lane + 128] + Ap[0][q][lane + 192];
#pragma unroll
        for (int m = 32; m >= 1; m >>= 1) p += __shfl_xor(p, m, 64);
        if (lane == 0) rA_s[q] = 1.0f / fmaxf(p, 2e-15f);
    }
    __syncthreads();

    // PV: wave w owns value rows [w*32, w*32+32) for ALL 4 q (no redundancy)
    {
        const int w = t >> 6, lane = t & 63;
        const float4* vb = (const float4*)(value + (size_t)b * S2_ * H_)
                           + (size_t)(w * 32) * (H_ / 4) + lane;
        float4 o[QB];
#pragma unroll
        for (int q = 0; q < QB; ++q) o[q] = make_float4(0.f, 0.f, 0.f, 0.f);
#pragma unroll 4
        for (int kk = 0; kk < 32; ++kk) {
            float4 v = vb[(size_t)kk * (H_ / 4)];
#pragma unroll
            for (int q = 0; q < QB; ++q) {
                float a = Ap[0][q][w * 32 + kk];
                o[q].x = fmaf(a, v.x, o[q].x); o[q].y = fmaf(a, v.y, o[q].y);
                o[q].z = fmaf(a, v.z, o[q].z); o[q].w = fmaf(a, v.w, o[q].w);
            }
        }
#pragma unroll
        for (int q = 0; q < QB; ++q) opart[w][q][lane] = o[q];
    }
    __syncthreads();

    // combine 8 partials, normalize, store
    if (t < QB * 64) {
        const int q = t >> 6, lane = t & 63;
        float4 s = make_float4(0.f, 0.f, 0.f, 0.f);
#pragma unroll
        for (int w = 0; w < 8; ++w) {
            float4 p = opart[w][q][lane];
            s.x += p.x; s.y += p.y; s.z += p.z; s.w += p.w;
        }
        const float r = rA_s[q];
        s.x *= r; s.y *= r; s.z *= r; s.w *= r;
        *(float4*)(out + (size_t)(b * S1_ + q0 + q) * H_ + lane * 4) = s;
    }
}

extern "C" void kernel_launch(void* const* d_in, const int* in_sizes, int n_in,
                              void* d_out, int out_size, void* d_ws, size_t ws_size,
                              hipStream_t stream) {
    const float* query  = (const float*)d_in[0];  // [16,128,256]
    const float* key    = (const float*)d_in[1];  // [16,256,256]
    const float* value  = (const float*)d_in[2];  // [16,256,256]
    const float* q_mask = (const float*)d_in[3];  // [16,128]
    const float* k_mask = (const float*)d_in[4];  // [16,256]
    const float* W1     = (const float*)d_in[5];  // [512,512]
    const float* b1     = (const float*)d_in[6];  // [512]
    const float* W2     = (const float*)d_in[7];  // [512,1]
    const float* b2     = (const float*)d_in[8];  // [1]
    float*       out    = (float*)d_out;

    _Float16* QPh  = (_Float16*)d_ws;                  // [2048][512]      2 MB
    _Float16* KPTh = QPh  + (size_t)B_ * S1_ * HM_;    // [16][64][256][8] 4 MB
    _Float16* WB   = KPTh + (size_t)B_ * S2_ * HM_;    // frag-order W   0.5 MB

    // WB = frag-order fp16 repack of W1 (both halves)
    cvtWB_kernel<<<128, 256, 0, stream>>>(W1, WB);

    // merged MFMA projections: blocks [0,128) -> QPh, [128,384) -> KPTh
    proj_mfma_kernel<<<384, 512, 0, stream>>>(query, key, WB, b1, QPh, KPTh);

    attn_kernel<<<dim3(S1_ / QB, B_), 512, 0, stream>>>(
        QPh, KPTh, value, q_mask, k_mask, W2, b2, out);
}